// Round 11
// baseline (199.927 us; speedup 1.0000x reference)
//
#include <hip/hip_runtime.h>
#include <hip/hip_fp16.h>

// dot_attention: out[b,n] = exp(diag*s - lse_n), s = (D/2)^-0.5 = 1/16.
// B=4, N=4096, D=512. Inputs fp32, output fp32.
// No fp32 MFMA on CDNA4 -> fp16 convert + mfma_f32_16x16x32_f16.
//
// R11 = R7 lse (best measured: 80.6us = 859 TF ~= the m97 source-HIP
// plateau; R5/R6/R9/R10 restructures all >= it) hardened + fused epilogue:
//  - explicit s_waitcnt vmcnt(0) before each __syncthreads (R8 determinism).
//  - finalize fused into lse: per-(b,rb) device-scope atomic counter; the
//    4th cs-sibling computes out for its 128 rows. Counter zeroed by
//    convert (prior dispatch). Producers: threadfence -> syncthreads ->
//    ACQ_REL fetch_add. Consumer: AGENT-scope atomic loads (per-XCD L2s
//    are not coherent; plain loads could hit stale poison lines).
//    Fixed-order sum -> bitwise-deterministic output.

typedef _Float16 f16x8 __attribute__((ext_vector_type(8)));  // MFMA A/B frag (4 VGPR)
typedef float    f32x4 __attribute__((ext_vector_type(4)));  // MFMA C/D frag

#define NB 4
#define NN 4096
#define ND 512
#define SCALE 0.0625f
#define LOG2E 1.4426950408889634f
#define NROWS (NB * NN)            // 16384
#define FRAG_B 1024                // bytes per packed fragment
#define GRP_B  16384               // bytes per 16-row group (16 frags)
#define TILE_B 32768               // 32-row tile = 2 groups
#define CPITCH 520                 // convert LDS row pitch (halfwords) = 1040 B
#define NCNT 128                   // (b, rb) rowgroup counters

__device__ __forceinline__ void gld16(const void* g, void* l) {
    __builtin_amdgcn_global_load_lds(
        (const __attribute__((address_space(1))) unsigned int*)g,
        (__attribute__((address_space(3))) unsigned int*)l, 16, 0, 0);
}

// Explicit DMA drain; never rely on compiler-inferred vmcnt for LDS-DMA
// consumption (R8 tripwire lesson).
__device__ __forceinline__ void vmfence() {
    asm volatile("s_waitcnt vmcnt(0)" ::: "memory");
}

__device__ __forceinline__ float aload(const float* p) {
    return __hip_atomic_load(p, __ATOMIC_RELAXED, __HIP_MEMORY_SCOPE_AGENT);
}

__device__ __forceinline__ f16x8 cvt8(float4 a, float4 b) {
    f16x8 r;
    r[0] = (_Float16)a.x; r[1] = (_Float16)a.y; r[2] = (_Float16)a.z; r[3] = (_Float16)a.w;
    r[4] = (_Float16)b.x; r[5] = (_Float16)b.y; r[6] = (_Float16)b.z; r[7] = (_Float16)b.w;
    return r;
}

__device__ __forceinline__ f16x8 cvt8s(float4 a, float4 b, float s) {
    f16x8 r;
    r[0] = (_Float16)(a.x * s); r[1] = (_Float16)(a.y * s);
    r[2] = (_Float16)(a.z * s); r[3] = (_Float16)(a.w * s);
    r[4] = (_Float16)(b.x * s); r[5] = (_Float16)(b.y * s);
    r[6] = (_Float16)(b.z * s); r[7] = (_Float16)(b.w * s);
    return r;
}

__device__ __forceinline__ float sel4(const f32x4& a, int j) {
    return (j == 0) ? a[0] : (j == 1) ? a[1] : (j == 2) ? a[2] : a[3];
}

// ---- kernel 1: kv fp32 -> fp16, packed in B-frag order via LDS transpose.
// One 16-row group per block (1024 blocks). frag(g,kt) byte lane*16 =
// kv[g*16 + (lane&15)][kt*32 + (lane>>4)*8 ..+8) as fp16.
// Also zeroes the lse epilogue counters (first NCNT blocks).
__launch_bounds__(256)
__global__ void convert_kernel(const float* __restrict__ kv,
                               _Float16* __restrict__ kvp,
                               int* __restrict__ cnt) {
    __shared__ _Float16 s[16 * CPITCH];
    const int g    = blockIdx.x;
    const int tid  = threadIdx.x;
    const int wid  = tid >> 6;
    const int lane = tid & 63;
    const int l15  = lane & 15;
    const int quad = lane >> 4;

    if (tid == 0 && g < NCNT) cnt[g] = 0;

    #pragma unroll
    for (int i = 0; i < 4; ++i) {
        const int r = wid * 4 + i;
        const float* src = kv + ((size_t)g * 16 + r) * ND + lane * 8;
        float4 a = *(const float4*)src;
        float4 b = *(const float4*)(src + 4);
        *(f16x8*)(s + r * CPITCH + lane * 8) = cvt8(a, b);
    }
    __syncthreads();

    _Float16* dst = kvp + (size_t)g * 8192 + lane * 8;
    #pragma unroll
    for (int p = 0; p < 4; ++p) {
        const int kt = wid * 4 + p;
        f16x8 v = *(const f16x8*)(s + l15 * CPITCH + kt * 32 + quad * 8);
        *(f16x8*)(dst + kt * 512) = v;
    }
}

// ---- kernel 2: per-row sum of exp(score) over a 1024-column split + diag
// + fused finalize (last cs-sibling). grid (16: b*4+cs, 32: rowblock) =
// 512 blocks, 256 threads = 4 waves, 2 blocks/CU (2x32KB dbuf), 2 waves/
// SIMD. Wave: 32 q-rows (Af 128 regs). Per iter: 32-row kv tile via DMA.
__launch_bounds__(256, 2)
__global__ void lse_partial_kernel(const float* __restrict__ q,
                                   const _Float16* __restrict__ kvp,
                                   float* __restrict__ partial,
                                   float* __restrict__ diagsc,
                                   int* __restrict__ cnt,
                                   float* __restrict__ out) {
    __shared__ char sbuf[2][TILE_B];
    __shared__ int lastflag;

    const int bc = blockIdx.x;          // b*4 + cs (fastest -> spread over XCDs)
    const int b  = bc >> 2;
    const int cs = bc & 3;
    const int rb = blockIdx.y;
    const int tid  = threadIdx.x;
    const int wid  = tid >> 6;
    const int lane = tid & 63;
    const int l15  = lane & 15;
    const int quad = lane >> 4;

    const int row0 = rb * 128 + wid * 32;    // wave's first q-row (in batch)
    // iteration whose 32-col kv tile coincides with this wave's 32 q-rows
    const int it_diag = ((row0 >> 10) == cs) ? ((row0 - cs * 1024) >> 5) : -1;

    // ---- A fragments: q fp32 -> fp16 scaled by s*log2e (exp2 path).
    f16x8 Af[2][16];
    #pragma unroll
    for (int m = 0; m < 2; ++m) {
        const float* qrow = q + ((size_t)(b * NN + row0 + m * 16 + l15)) * ND + quad * 8;
        #pragma unroll
        for (int k = 0; k < 16; ++k) {
            float4 u0 = *(const float4*)(qrow + k * 32);
            float4 u1 = *(const float4*)(qrow + k * 32 + 4);
            Af[m][k] = cvt8s(u0, u1, SCALE * LOG2E);
        }
    }

    float lacc[2][4];
    #pragma unroll
    for (int m = 0; m < 2; ++m)
        #pragma unroll
        for (int j = 0; j < 4; ++j)
            lacc[m][j] = 0.f;

    // packed base for this (b,cs): groups [b*256 + cs*64, +64) = 32 tiles
    const char* pb  = (const char*)kvp + ((size_t)(b * 256 + cs * 64)) * GRP_B;
    const char* ssb = pb + (size_t)lane * 16;

    // stage 32-frag tile `it_` into sbuf[buf_]: 8 frag-DMAs per wave
    #define STAGE(it_, buf_)                                                  \
        do {                                                                  \
            const char* sp_ = ssb + (size_t)(it_) * TILE_B;                   \
            char* lb_ = sbuf[buf_];                                           \
            _Pragma("unroll")                                                 \
            for (int p_ = 0; p_ < 8; ++p_) {                                  \
                int f_ = wid * 8 + p_;                                        \
                gld16(sp_ + f_ * FRAG_B, lb_ + f_ * FRAG_B);                  \
            }                                                                 \
        } while (0)

    STAGE(0, 0);
    int buf = 0;

    for (int it = 0; it < 32; ++it) {
        vmfence();                            // this wave's DMA drained
        __syncthreads();                      // all waves' tile-`it` visible
        if (it + 1 < 32) STAGE(it + 1, buf ^ 1);

        const char* lb = sbuf[buf] + (size_t)lane * 16;
        f32x4 acc[2][2];
        #pragma unroll
        for (int m = 0; m < 2; ++m)
            #pragma unroll
            for (int nf = 0; nf < 2; ++nf)
                acc[m][nf] = (f32x4){0.f, 0.f, 0.f, 0.f};

        #pragma unroll
        for (int kt = 0; kt < 16; ++kt) {
            f16x8 b0 = *(const f16x8*)(lb + kt * FRAG_B);
            f16x8 b1 = *(const f16x8*)(lb + GRP_B + kt * FRAG_B);
            acc[0][0] = __builtin_amdgcn_mfma_f32_16x16x32_f16(Af[0][kt], b0, acc[0][0], 0, 0, 0);
            acc[1][0] = __builtin_amdgcn_mfma_f32_16x16x32_f16(Af[1][kt], b0, acc[1][0], 0, 0, 0);
            acc[0][1] = __builtin_amdgcn_mfma_f32_16x16x32_f16(Af[0][kt], b1, acc[0][1], 0, 0, 0);
            acc[1][1] = __builtin_amdgcn_mfma_f32_16x16x32_f16(Af[1][kt], b1, acc[1][1], 0, 0, 0);
        }

        // diag: C/D row = quad*4+j, col = nf*16+l15; aligned iter => nf==m,
        // l15 == quad*4+j.
        if (it == it_diag) {
            if ((l15 >> 2) == quad) {
                const int j = l15 & 3;
                diagsc[b * NN + row0 + l15]      = sel4(acc[0][0], j);
                diagsc[b * NN + row0 + 16 + l15] = sel4(acc[1][1], j);
            }
        }

        // acc = score*log2e -> exp(score) = exp2(acc)
        #pragma unroll
        for (int m = 0; m < 2; ++m)
            #pragma unroll
            for (int nf = 0; nf < 2; ++nf)
                #pragma unroll
                for (int j = 0; j < 4; ++j)
                    lacc[m][j] += __builtin_amdgcn_exp2f(acc[m][nf][j]);

        buf ^= 1;
    }

    // reduce over the 16 columns held across l15 lanes
    #pragma unroll
    for (int m = 0; m < 2; ++m)
        #pragma unroll
        for (int j = 0; j < 4; ++j) {
            float v = lacc[m][j];
            v += __shfl_xor(v, 1, 64);
            v += __shfl_xor(v, 2, 64);
            v += __shfl_xor(v, 4, 64);
            v += __shfl_xor(v, 8, 64);
            if (l15 == 0)
                partial[(size_t)cs * NROWS + b * NN + row0 + m * 16 + quad * 4 + j] = v;
        }

    // ---- fused finalize: last of the 4 cs-siblings for (b, rb) computes out.
    __threadfence();                          // release partial/diag stores
    __syncthreads();                          // all threads' stores fenced
    if (tid == 0) {
        int prev = __hip_atomic_fetch_add(&cnt[b * 32 + rb], 1,
                                          __ATOMIC_ACQ_REL,
                                          __HIP_MEMORY_SCOPE_AGENT);
        lastflag = (prev == 3);
    }
    __syncthreads();
    if (lastflag && tid < 128) {
        const int row = b * NN + rb * 128 + tid;   // global row
        float l = aload(partial + row) +
                  aload(partial + NROWS + row) +
                  aload(partial + 2 * NROWS + row) +
                  aload(partial + 3 * NROWS + row);
        float d = aload(diagsc + row);
        out[row] = exp2f(d) / l;
    }
}

extern "C" void kernel_launch(void* const* d_in, const int* in_sizes, int n_in,
                              void* d_out, int out_size, void* d_ws, size_t ws_size,
                              hipStream_t stream) {
    const float* q  = (const float*)d_in[0];
    const float* kv = (const float*)d_in[1];
    float* out = (float*)d_out;

    // ws: kvp fp16 packed [16MB] | partial f32[4][16384] | diagsc f32[16384]
    //     | cnt int[128]
    _Float16* kvp   = (_Float16*)d_ws;
    float* partial  = (float*)((char*)d_ws + (size_t)NROWS * ND * 2);
    float* diagsc   = partial + 4 * NROWS;
    int*   cnt      = (int*)(diagsc + NROWS);

    convert_kernel<<<1024, 256, 0, stream>>>(kv, kvp, cnt);
    lse_partial_kernel<<<dim3(16, 32), 256, 0, stream>>>(q, kvp, partial,
                                                         diagsc, cnt, out);
}